// Round 4
// baseline (1811.960 us; speedup 1.0000x reference)
//
#include <hip/hip_runtime.h>
#include <cstdint>

#define NB 16      // clouds
#define NP 4096    // points per cloud
#define MC 1024    // FPS centers per cloud
#define KNN 64     // neighbors
#define CIN 64     // input feature dim
#define HID 64
#define OUTD 128

typedef __attribute__((ext_vector_type(8))) short bf16x8;
typedef __attribute__((ext_vector_type(4))) float f32x4;
typedef unsigned long long ull;
typedef unsigned short ushort_t;

// Bit-exact (vs numpy f32) squared distance: no FMA contraction, numpy sum order.
__device__ __forceinline__ float dist2e(float ax, float ay, float az,
                                        float bx, float by, float bz) {
  float dx = __fsub_rn(ax, bx);
  float dy = __fsub_rn(ay, by);
  float dz = __fsub_rn(az, bz);
  return __fadd_rn(__fadd_rn(__fmul_rn(dx, dx), __fmul_rn(dy, dy)), __fmul_rn(dz, dz));
}

// f32 -> bf16 with round-to-nearest-even (don't trust header rounding mode).
__device__ __forceinline__ ushort_t f2bf(float f) {
  unsigned u = __float_as_uint(f);
  unsigned r = (u + 0x7FFFu + ((u >> 16) & 1u)) >> 16;
  return (ushort_t)r;
}

// ---- DPP helpers: 64-bit key max-reduce on the VALU pipe (no DS-pipe shuffles) ----
template <int CTRL>
__device__ __forceinline__ ull kshift(ull k) {
  int lo = (int)(unsigned)(k & 0xffffffffULL);
  int hi = (int)(unsigned)(k >> 32);
  lo = __builtin_amdgcn_update_dpp(lo, lo, CTRL, 0xf, 0xf, false);
  hi = __builtin_amdgcn_update_dpp(hi, hi, CTRL, 0xf, 0xf, false);
  return ((ull)(unsigned)hi << 32) | (ull)(unsigned)lo;
}
template <int CTRL>
__device__ __forceinline__ ull kred(ull k) {
  ull o = kshift<CTRL>(k);
  return (o > k) ? o : k;
}

// ---------------- Kernel 1: exact FPS, one block (256 thr = 4 waves) per cloud ----------------
// key = dbits<<20 | (4095-gi)<<8 | (it&0xFF) : u64 max == (max d, tie -> lowest idx),
// low byte = iteration tag for the barrier-free spin-ring handoff.
// No s_barrier in the loop: each wave writes its candidate (coords first, then tagged
// key; DS pipe is in-order per wave) to a depth-4 LDS ring and spin-polls the other
// waves' slots. Max skew is structurally 1 iteration; ring reuse distance 4 + 8-bit
// tag => no ABA. Winner coords ride the ring => no dependent pts[w] read in the loop.
__global__ __launch_bounds__(256) void fps_kernel(
    const float* __restrict__ point,
    float* __restrict__ ctr, float* __restrict__ cent_out, float* __restrict__ batch_out) {
  const int b = blockIdx.x;
  const int t = threadIdx.x;
  const int lane = t & 63, wid = t >> 6;
  __shared__ float4 pts[NP];          // 64 KB
  __shared__ ull ringk[4][4];         // [it&3][wave] tagged keys
  __shared__ float4 ringc[4][4];      // [it&3][wave] candidate coords
  __shared__ int whist[MC];           // 4 KB
  const float* p = point + (size_t)b * NP * 3;
  for (int i = t; i < NP; i += 256) {
    float4 v; v.x = p[3 * i]; v.y = p[3 * i + 1]; v.z = p[3 * i + 2]; v.w = 0.f;
    pts[i] = v;
  }
  if (t < 16) ringk[t >> 2][t & 3] = 0ull;  // sentinel tag 0; first uses are tags 1..4
  if (t == 0) whist[0] = 0;                 // sample 0 is index 0
  __syncthreads();
  float qx[16], qy[16], qz[16], d[16];
#pragma unroll
  for (int r = 0; r < 16; ++r) {
    float4 v = pts[t * 16 + r];
    qx[r] = v.x; qy[r] = v.y; qz[r] = v.z;
    d[r] = __int_as_float(0x7f800000);  // +inf; min(inf, d0) == d0 exactly
  }
  float wpx = pts[0].x, wpy = pts[0].y, wpz = pts[0].z;  // current center coords
  for (int it = 1; it < MC; ++it) {
    float bd = -1.0f; int br = 0;
#pragma unroll
    for (int r = 0; r < 16; ++r) {       // fused min-update + local argmax (first-max wins)
      float nd = dist2e(qx[r], qy[r], qz[r], wpx, wpy, wpz);
      float dv = fminf(d[r], nd);
      d[r] = dv;
      if (dv > bd) { bd = dv; br = r; }
    }
    const unsigned gi = (unsigned)(t * 16 + br);
    const ull tag = (ull)(unsigned)(it & 0xFF);
    const ull mykey = ((ull)__float_as_uint(bd) << 20) |
                      ((ull)((~gi) & 0xFFFu) << 8) | tag;
    ull key = mykey;
    key = kred<0x111>(key);  // row_shr:1
    key = kred<0x112>(key);  // row_shr:2
    key = kred<0x114>(key);  // row_shr:4
    key = kred<0x118>(key);  // row_shr:8   -> lane 15/31/47/63 = row max
    key = kred<0x142>(key);  // row_bcast:15
    key = kred<0x143>(key);  // row_bcast:31 -> lane 63 = wave max
    const unsigned wk_lo = (unsigned)__builtin_amdgcn_readlane((int)(unsigned)(key & 0xffffffffULL), 63);
    const unsigned wk_hi = (unsigned)__builtin_amdgcn_readlane((int)(unsigned)(key >> 32), 63);
    const ull wkey = ((ull)wk_hi << 32) | (ull)wk_lo;
    const int slot = it & 3;
    if (mykey == wkey) {  // exactly one lane (gi unique in key)
      volatile float* cc = (volatile float*)&ringc[slot][wid];
      cc[0] = qx[br]; cc[1] = qy[br]; cc[2] = qz[br];   // coords BEFORE key
      *(volatile ull*)&ringk[slot][wid] = wkey;
    }
    // spin-poll all 4 wave slots for this iteration's tag
    volatile ull* rk = &ringk[slot][0];
    ull s0, s1, s2, s3;
    do {
      s0 = rk[0]; s1 = rk[1]; s2 = rk[2]; s3 = rk[3];
    } while ((((unsigned)s0 ^ (unsigned)tag) | ((unsigned)s1 ^ (unsigned)tag) |
              ((unsigned)s2 ^ (unsigned)tag) | ((unsigned)s3 ^ (unsigned)tag)) & 0xFFu);
    volatile float4* rc = (volatile float4*)&ringc[slot][0];
    float4 c0, c1, c2, c3;
    c0.x = rc[0].x; c0.y = rc[0].y; c0.z = rc[0].z;
    c1.x = rc[1].x; c1.y = rc[1].y; c1.z = rc[1].z;
    c2.x = rc[2].x; c2.y = rc[2].y; c2.z = rc[2].z;
    c3.x = rc[3].x; c3.y = rc[3].y; c3.z = rc[3].z;
    ull ka = s0; float4 ca = c0;
    if (s1 > ka) { ka = s1; ca = c1; }
    ull kc = s2; float4 cb = c2;
    if (s3 > kc) { kc = s3; cb = c3; }
    if (kc > ka) { ka = kc; ca = cb; }
    const int w = 4095 - (int)((ka >> 8) & 0xFFFu);
    wpx = ca.x; wpy = ca.y; wpz = ca.z;
    if (t == 0) whist[it] = w;
  }
  __syncthreads();                          // skew <= 1 iter; converge for epilogue
  for (int s = t; s < MC; s += 256) {       // one-shot output writeback
    int wi = whist[s];
    float4 wp = pts[wi];
    size_t o = (size_t)b * MC + s;
    ctr[3*o] = wp.x; ctr[3*o+1] = wp.y; ctr[3*o+2] = wp.z;
    cent_out[3*o] = wp.x; cent_out[3*o+1] = wp.y; cent_out[3*o+2] = wp.z;
    batch_out[o] = (float)b;  // batch = arange // NP == cloud index
  }
}

// ------------- Kernel 2: radius + K-nearest selection, one wave per center -------------
__global__ void neigh_kernel(const float* __restrict__ point,
                             const float* __restrict__ ctr,
                             int* __restrict__ nidx, int* __restrict__ ncnt) {
  const int c = blockIdx.x;
  const int b = c >> 10;  // c / MC
  const int lane = threadIdx.x;  // 64 threads = 1 wave
  __shared__ float ld[512];
  __shared__ int li[512];
  const float R2 = (float)(0.2 * 0.2);
  const float cx = ctr[3*c], cy = ctr[3*c+1], cz = ctr[3*c+2];
  const float* p = point + (size_t)b * NP * 3;
  int cnt = 0;
  for (int s = 0; s < NP / 64; ++s) {
    int j = s * 64 + lane;
    float d2 = dist2e(cx, cy, cz, p[3*j], p[3*j+1], p[3*j+2]);
    bool v = d2 < R2;
    unsigned long long m = __ballot(v);
    if (v) {
      int pos = cnt + __popcll(m & ((1ull << lane) - 1ull));
      if (pos < 512) { ld[pos] = d2; li[pos] = j; }
    }
    cnt += __popcll(m);
  }
  if (cnt > 512) cnt = 512;
  __syncthreads();
  if (cnt <= KNN) {
    nidx[(size_t)c * KNN + lane] = (lane < cnt) ? li[lane] : 0;
  } else {
    float od[8]; int oi[8];
#pragma unroll
    for (int r = 0; r < 8; ++r) {
      int s2 = lane + r * 64;
      if (s2 < cnt) { od[r] = ld[s2]; oi[r] = li[s2]; }
      else { od[r] = __int_as_float(0x7f800000); oi[r] = 0x7fffffff; }
    }
    for (int round = 0; round < KNN; ++round) {
      float bd = __int_as_float(0x7f800000); int bi = 0x7fffffff;
#pragma unroll
      for (int r = 0; r < 8; ++r)
        if (od[r] < bd || (od[r] == bd && oi[r] < bi)) { bd = od[r]; bi = oi[r]; }
#pragma unroll
      for (int off = 32; off > 0; off >>= 1) {
        float o2 = __shfl_down(bd, off);
        int i2 = __shfl_down(bi, off);
        if (o2 < bd || (o2 == bd && i2 < bi)) { bd = o2; bi = i2; }
      }
      bi = __shfl(bi, 0);
      if (lane == 0) nidx[(size_t)c * KNN + round] = bi;
#pragma unroll
      for (int r = 0; r < 8; ++r) if (oi[r] == bi) od[r] = __int_as_float(0x7f800000);
    }
  }
  if (lane == 0) ncnt[c] = (cnt < KNN) ? cnt : KNN;
}

// ---------- Prep: xyz f32 -> bf16, and W1/W2/W3 -> MFMA B-fragment layout in ws ----------
__device__ __forceinline__ void wfrag_entry(const float* __restrict__ W,
                                            ushort_t* __restrict__ out,
                                            int e, int KS, int K, int N) {
  int lane = e & 63, t2 = e >> 6;
  int ks = t2 % KS, nt = t2 / KS;
  int n = nt * 16 + (lane & 15);
  int kb = ks * 32 + ((lane >> 4) & 3) * 8;
#pragma unroll
  for (int j = 0; j < 8; ++j) {
    int k = kb + j;
    float v = (k < K) ? W[(size_t)k * N + n] : 0.f;
    out[(size_t)e * 8 + j] = f2bf(v);
  }
}

__global__ __launch_bounds__(256) void prep_kernel(
    const float* __restrict__ xyz,
    const float* __restrict__ W1, const float* __restrict__ W2, const float* __restrict__ W3,
    ushort_t* __restrict__ xyzbf, ushort_t* __restrict__ w1f,
    ushort_t* __restrict__ w2f, ushort_t* __restrict__ w3f) {
  const int blk = blockIdx.x, t = threadIdx.x;
  if (blk < 4096) {
    size_t i = ((size_t)blk * 256 + t) * 4;
    float4 v = *(const float4*)(xyz + i);
    unsigned lo = (unsigned)f2bf(v.x) | ((unsigned)f2bf(v.y) << 16);
    unsigned hi = (unsigned)f2bf(v.z) | ((unsigned)f2bf(v.w) << 16);
    uint2 o; o.x = lo; o.y = hi;
    *(uint2*)(xyzbf + i) = o;
  } else {
    for (int e = t; e < 4 * 3 * 64; e += 256) wfrag_entry(W1, w1f, e, 3, CIN + 3, HID);
    for (int e = t; e < 4 * 2 * 64; e += 256) wfrag_entry(W2, w2f, e, 2, HID, HID);
    for (int e = t; e < 8 * 2 * 64; e += 256) wfrag_entry(W3, w3f, e, 2, HID, OUTD);
  }
}

// ---------- Kernel 3: MFMA bf16 MLP, one wave per center, 4 centers/block ----------
#define HSTRIDE 72   // bf16 elems per hbuf row: 144 B = 16B-aligned, 2-way-conflict-free b128
__global__ __launch_bounds__(256) void mlp_kernel(
    const ushort_t* __restrict__ xyzbf, const float* __restrict__ point,
    const float* __restrict__ ctr, const int* __restrict__ nidx,
    const int* __restrict__ ncnt,
    const ushort_t* __restrict__ w1f, const ushort_t* __restrict__ w2f,
    const ushort_t* __restrict__ w3f,
    const float* __restrict__ b1, const float* __restrict__ b2,
    const float* __restrict__ b3,
    float* __restrict__ out) {
  const int wv = threadIdx.x >> 6, lane = threadIdx.x & 63;
  const int quad = lane >> 4, col16 = lane & 15;
  const int c = blockIdx.x * 4 + wv;
  const int bcl = c >> 10;
  const size_t bbase = (size_t)bcl * NP;
  __shared__ ushort_t hbuf_all[4 * 64 * HSTRIDE];  // 36864 B, wave-private slices
  ushort_t* hb = hbuf_all + wv * 64 * HSTRIDE;

  const int jg = nidx[(size_t)c * KNN + lane];
  const int nv = ncnt[c];
  const float cx = ctr[3*c], cy = ctr[3*c+1], cz = ctr[3*c+2];
  const float* pp = point + (bbase + jg) * 3;
  const float dx = pp[0] - cx, dy = pp[1] - cy, dz = pp[2] - cz;

  bf16x8 a1[4][2];
  bf16x8 a2[4];
#pragma unroll
  for (int mt = 0; mt < 4; ++mt) {
    int srcl = mt * 16 + col16;
    int jmt = __shfl(jg, srcl);
    const ushort_t* rp = xyzbf + (bbase + (size_t)jmt) * CIN + quad * 8;
    a1[mt][0] = *(const bf16x8*)(rp);
    a1[mt][1] = *(const bf16x8*)(rp + 32);
    float ddx = __shfl(dx, srcl), ddy = __shfl(dy, srcl), ddz = __shfl(dz, srcl);
    bf16x8 t2 = {0, 0, 0, 0, 0, 0, 0, 0};
    if (quad == 0) {
      t2[0] = (short)f2bf(ddx); t2[1] = (short)f2bf(ddy); t2[2] = (short)f2bf(ddz);
    }
    a2[mt] = t2;
  }

  bf16x8 bw1[4][3];
#pragma unroll
  for (int nt = 0; nt < 4; ++nt)
#pragma unroll
    for (int ks = 0; ks < 3; ++ks)
      bw1[nt][ks] = *(const bf16x8*)(w1f + ((size_t)(nt * 3 + ks) * 64 + lane) * 8);
  f32x4 acc1[4][4];
#pragma unroll
  for (int nt = 0; nt < 4; ++nt) {
    float bv = b1[nt * 16 + col16];
#pragma unroll
    for (int mt = 0; mt < 4; ++mt) { f32x4 v = {bv, bv, bv, bv}; acc1[mt][nt] = v; }
  }
#pragma unroll
  for (int mt = 0; mt < 4; ++mt)
#pragma unroll
    for (int nt = 0; nt < 4; ++nt) {
      acc1[mt][nt] = __builtin_amdgcn_mfma_f32_16x16x32_bf16(a1[mt][0], bw1[nt][0], acc1[mt][nt], 0, 0, 0);
      acc1[mt][nt] = __builtin_amdgcn_mfma_f32_16x16x32_bf16(a1[mt][1], bw1[nt][1], acc1[mt][nt], 0, 0, 0);
      acc1[mt][nt] = __builtin_amdgcn_mfma_f32_16x16x32_bf16(a2[mt],    bw1[nt][2], acc1[mt][nt], 0, 0, 0);
    }
#pragma unroll
  for (int mt = 0; mt < 4; ++mt)
#pragma unroll
    for (int nt = 0; nt < 4; ++nt)
#pragma unroll
      for (int reg = 0; reg < 4; ++reg) {
        int row = quad * 4 + reg + mt * 16;
        hb[row * HSTRIDE + col16 + nt * 16] = f2bf(fmaxf(acc1[mt][nt][reg], 0.f));
      }

  bf16x8 a21[4][2];
#pragma unroll
  for (int mt = 0; mt < 4; ++mt)
#pragma unroll
    for (int ks = 0; ks < 2; ++ks)
      a21[mt][ks] = *(const bf16x8*)(hb + (col16 + mt * 16) * HSTRIDE + ks * 32 + quad * 8);
  bf16x8 bw2[4][2];
#pragma unroll
  for (int nt = 0; nt < 4; ++nt)
#pragma unroll
    for (int ks = 0; ks < 2; ++ks)
      bw2[nt][ks] = *(const bf16x8*)(w2f + ((size_t)(nt * 2 + ks) * 64 + lane) * 8);
  f32x4 acc2[4][4];
#pragma unroll
  for (int nt = 0; nt < 4; ++nt) {
    float bv = b2[nt * 16 + col16];
#pragma unroll
    for (int mt = 0; mt < 4; ++mt) { f32x4 v = {bv, bv, bv, bv}; acc2[mt][nt] = v; }
  }
#pragma unroll
  for (int mt = 0; mt < 4; ++mt)
#pragma unroll
    for (int nt = 0; nt < 4; ++nt) {
      acc2[mt][nt] = __builtin_amdgcn_mfma_f32_16x16x32_bf16(a21[mt][0], bw2[nt][0], acc2[mt][nt], 0, 0, 0);
      acc2[mt][nt] = __builtin_amdgcn_mfma_f32_16x16x32_bf16(a21[mt][1], bw2[nt][1], acc2[mt][nt], 0, 0, 0);
    }
#pragma unroll
  for (int mt = 0; mt < 4; ++mt)
#pragma unroll
    for (int nt = 0; nt < 4; ++nt)
#pragma unroll
      for (int reg = 0; reg < 4; ++reg) {
        int row = quad * 4 + reg + mt * 16;
        hb[row * HSTRIDE + col16 + nt * 16] = f2bf(fmaxf(acc2[mt][nt][reg], 0.f));
      }

  bf16x8 a3[4][2];
#pragma unroll
  for (int mt = 0; mt < 4; ++mt)
#pragma unroll
    for (int ks = 0; ks < 2; ++ks)
      a3[mt][ks] = *(const bf16x8*)(hb + (col16 + mt * 16) * HSTRIDE + ks * 32 + quad * 8);
#pragma unroll
  for (int pass = 0; pass < 2; ++pass) {
    bf16x8 bw3[4][2];
#pragma unroll
    for (int nt = 0; nt < 4; ++nt)
#pragma unroll
      for (int ks = 0; ks < 2; ++ks)
        bw3[nt][ks] = *(const bf16x8*)(w3f + ((size_t)((pass * 4 + nt) * 2 + ks) * 64 + lane) * 8);
    f32x4 acc3[4][4];
#pragma unroll
    for (int nt = 0; nt < 4; ++nt) {
      float bv = b3[pass * 64 + nt * 16 + col16];
#pragma unroll
      for (int mt = 0; mt < 4; ++mt) { f32x4 v = {bv, bv, bv, bv}; acc3[mt][nt] = v; }
    }
#pragma unroll
    for (int mt = 0; mt < 4; ++mt)
#pragma unroll
      for (int nt = 0; nt < 4; ++nt) {
        acc3[mt][nt] = __builtin_amdgcn_mfma_f32_16x16x32_bf16(a3[mt][0], bw3[nt][0], acc3[mt][nt], 0, 0, 0);
        acc3[mt][nt] = __builtin_amdgcn_mfma_f32_16x16x32_bf16(a3[mt][1], bw3[nt][1], acc3[mt][nt], 0, 0, 0);
      }
#pragma unroll
    for (int nt = 0; nt < 4; ++nt) {
      float m = -1.0e30f;
#pragma unroll
      for (int mt = 0; mt < 4; ++mt)
#pragma unroll
        for (int reg = 0; reg < 4; ++reg) {
          int row = quad * 4 + reg + mt * 16;
          float v = fmaxf(acc3[mt][nt][reg], 0.f);
          m = fmaxf(m, (row < nv) ? v : -1.0e30f);
        }
      m = fmaxf(m, __shfl_xor(m, 16));
      m = fmaxf(m, __shfl_xor(m, 32));
      if (quad == 0)
        out[(size_t)c * OUTD + pass * 64 + nt * 16 + col16] = m;
    }
  }
}

extern "C" void kernel_launch(void* const* d_in, const int* in_sizes, int n_in,
                              void* d_out, int out_size, void* d_ws, size_t ws_size,
                              hipStream_t stream) {
  const float* xyz   = (const float*)d_in[0];
  const float* point = (const float*)d_in[1];
  // d_in[2] = batch (values == cloud index by construction), d_in[3] = num_samples (64)
  const float* W1 = (const float*)d_in[4];
  const float* b1 = (const float*)d_in[5];
  const float* W2 = (const float*)d_in[6];
  const float* b2 = (const float*)d_in[7];
  const float* W3 = (const float*)d_in[8];
  const float* b3 = (const float*)d_in[9];

  float* out       = (float*)d_out;                     // [16384,128]
  float* cent_out  = out + (size_t)NB * MC * OUTD;      // [16384,3]
  float* batch_out = cent_out + (size_t)NB * MC * 3;    // [16384] (f32 values)

  char* ws = (char*)d_ws;
  float* ctr       = (float*)(ws);                          // 196608 B
  int*   nidx      = (int*)(ws + 196608);                   // 4 MB
  int*   ncnt      = (int*)(ws + 196608 + 4194304);         // 64 KB
  ushort_t* xyzbf  = (ushort_t*)(ws + 4456448);             // 8 MB
  ushort_t* w1f    = (ushort_t*)(ws + 4456448 + 8388608);   // 12288 B
  ushort_t* w2f    = (ushort_t*)(ws + 12845056 + 12288);    // 8192 B
  ushort_t* w3f    = (ushort_t*)(ws + 12857344 + 8192);     // 16384 B

  prep_kernel<<<4097, 256, 0, stream>>>(xyz, W1, W2, W3, xyzbf, w1f, w2f, w3f);
  fps_kernel<<<NB, 256, 0, stream>>>(point, ctr, cent_out, batch_out);
  neigh_kernel<<<NB * MC, 64, 0, stream>>>(point, ctr, nidx, ncnt);
  mlp_kernel<<<NB * MC / 4, 256, 0, stream>>>(xyzbf, point, ctr, nidx, ncnt,
                                              w1f, w2f, w3f, b1, b2, b3, out);
}

// Round 5
// 1595.110 us; speedup vs baseline: 1.1359x; 1.1359x over previous
//
#include <hip/hip_runtime.h>
#include <cstdint>

#define NB 16      // clouds
#define NP 4096    // points per cloud
#define MC 1024    // FPS centers per cloud
#define KNN 64     // neighbors
#define CIN 64     // input feature dim
#define HID 64
#define OUTD 128

typedef __attribute__((ext_vector_type(8))) short bf16x8;
typedef __attribute__((ext_vector_type(4))) float f32x4;
typedef unsigned long long ull;
typedef unsigned short ushort_t;

#define F32_INF __int_as_float(0x7f800000)

// Bit-exact (vs numpy f32) squared distance: no FMA contraction, numpy sum order.
__device__ __forceinline__ float dist2e(float ax, float ay, float az,
                                        float bx, float by, float bz) {
  float dx = __fsub_rn(ax, bx);
  float dy = __fsub_rn(ay, by);
  float dz = __fsub_rn(az, bz);
  return __fadd_rn(__fadd_rn(__fmul_rn(dx, dx), __fmul_rn(dy, dy)), __fmul_rn(dz, dz));
}

// f32 -> bf16 with round-to-nearest-even.
__device__ __forceinline__ ushort_t f2bf(float f) {
  unsigned u = __float_as_uint(f);
  unsigned r = (u + 0x7FFFu + ((u >> 16) & 1u)) >> 16;
  return (ushort_t)r;
}

// ---- DPP helpers: 64-bit key max-reduce on the VALU pipe (no DS-pipe shuffles) ----
template <int CTRL>
__device__ __forceinline__ ull kshift(ull k) {
  int lo = (int)(unsigned)(k & 0xffffffffULL);
  int hi = (int)(unsigned)(k >> 32);
  lo = __builtin_amdgcn_update_dpp(lo, lo, CTRL, 0xf, 0xf, false);
  hi = __builtin_amdgcn_update_dpp(hi, hi, CTRL, 0xf, 0xf, false);
  return ((ull)(unsigned)hi << 32) | (ull)(unsigned)lo;
}
template <int CTRL>
__device__ __forceinline__ ull kred(ull k) {
  ull o = kshift<CTRL>(k);
  return (o > k) ? o : k;
}
// full 64-lane max -> valid in lane 63
__device__ __forceinline__ ull kred_all(ull k) {
  k = kred<0x111>(k);  // row_shr:1
  k = kred<0x112>(k);  // row_shr:2
  k = kred<0x114>(k);  // row_shr:4
  k = kred<0x118>(k);  // row_shr:8
  k = kred<0x142>(k);  // row_bcast:15
  k = kred<0x143>(k);  // row_bcast:31
  return k;
}

// ---------- Prep helper: W -> MFMA B-fragment layout ----------
__device__ __forceinline__ void wfrag_entry(const float* __restrict__ W,
                                            ushort_t* __restrict__ out,
                                            int e, int KS, int K, int N) {
  int lane = e & 63, t2 = e >> 6;
  int ks = t2 % KS, nt = t2 / KS;
  int n = nt * 16 + (lane & 15);
  int kb = ks * 32 + ((lane >> 4) & 3) * 8;
#pragma unroll
  for (int j = 0; j < 8; ++j) {
    int k = kb + j;
    float v = (k < K) ? W[(size_t)k * N + n] : 0.f;
    out[(size_t)e * 8 + j] = f2bf(v);
  }
}

// ============ Kernel 1 (fused): FPS (blocks 0..7, 2 clouds each) + prep (rest) ============
// FPS: round-3 barrier structure, but TWO independent clouds interleaved per block.
// Cloud B's dist/reduce work issues during cloud A's LDS/barrier stalls.
// key = (f32bits(d) << 32) | ~gi : u64 max == (max d, tie -> lowest idx).
__global__ __launch_bounds__(512) void fps_prep_kernel(
    const float* __restrict__ point, const float* __restrict__ xyz,
    const float* __restrict__ W1, const float* __restrict__ W2, const float* __restrict__ W3,
    float* __restrict__ ctr, float* __restrict__ cent_out, float* __restrict__ batch_out,
    ushort_t* __restrict__ xyzbf, ushort_t* __restrict__ w1f,
    ushort_t* __restrict__ w2f, ushort_t* __restrict__ w3f) {
  const int blk = blockIdx.x;
  const int t = threadIdx.x;
  if (blk >= NB / 2) {  // ---- prep path (independent of FPS; runs on idle CUs) ----
    const int pb = blk - NB / 2;
    if (pb < 2048) {
      size_t i = ((size_t)pb * 512 + t) * 4;
      float4 v = *(const float4*)(xyz + i);
      unsigned lo = (unsigned)f2bf(v.x) | ((unsigned)f2bf(v.y) << 16);
      unsigned hi = (unsigned)f2bf(v.z) | ((unsigned)f2bf(v.w) << 16);
      uint2 o; o.x = lo; o.y = hi;
      *(uint2*)(xyzbf + i) = o;
    } else {
      for (int e = t; e < 4 * 3 * 64; e += 512) wfrag_entry(W1, w1f, e, 3, CIN + 3, HID);
      for (int e = t; e < 4 * 2 * 64; e += 512) wfrag_entry(W2, w2f, e, 2, HID, HID);
      for (int e = t; e < 8 * 2 * 64; e += 512) wfrag_entry(W3, w3f, e, 2, HID, OUTD);
    }
    return;
  }
  // ---- FPS path: clouds bA = 2*blk, bB = 2*blk+1; 8 waves, 8 pts/lane/cloud ----
  const int lane = t & 63, wid = t >> 6;
  const int bA = 2 * blk, bB = 2 * blk + 1;
  __shared__ float xA[NP], yA[NP], zA[NP];   // SoA: uniform pts[w] = 3 overlapped b32
  __shared__ float xB[NP], yB[NP], zB[NP];   // 96 KB total
  __shared__ int whA[MC], whB[MC];           // 8 KB
  __shared__ ull kbA[2][8], kbB[2][8];       // parity-double-buffered wave keys
  const float* pA = point + (size_t)bA * NP * 3;
  const float* pB = point + (size_t)bB * NP * 3;
  for (int i = t; i < NP; i += 512) {
    xA[i] = pA[3*i]; yA[i] = pA[3*i+1]; zA[i] = pA[3*i+2];
    xB[i] = pB[3*i]; yB[i] = pB[3*i+1]; zB[i] = pB[3*i+2];
  }
  if (t == 0) { whA[0] = 0; whB[0] = 0; }   // sample 0 is index 0
  __syncthreads();
  float ax[8], ay[8], az[8], da[8];
  float bx[8], by[8], bz[8], db[8];
#pragma unroll
  for (int r = 0; r < 8; ++r) {
    int i = t * 8 + r;
    ax[r] = xA[i]; ay[r] = yA[i]; az[r] = zA[i]; da[r] = F32_INF;
    bx[r] = xB[i]; by[r] = yB[i]; bz[r] = zB[i]; db[r] = F32_INF;
  }
  float wAx = xA[0], wAy = yA[0], wAz = zA[0];
  float wBx = xB[0], wBy = yB[0], wBz = zB[0];
  for (int it = 1; it < MC; ++it) {
    const int par = it & 1;
    float bdA = -1.f; unsigned giA = 0;
    float bdB = -1.f; unsigned giB = 0;
#pragma unroll
    for (int r = 0; r < 8; ++r) {   // fused min-update + first-max argmax, both clouds
      float ndA = dist2e(ax[r], ay[r], az[r], wAx, wAy, wAz);
      float dvA = fminf(da[r], ndA);
      da[r] = dvA;
      if (dvA > bdA) { bdA = dvA; giA = (unsigned)(t * 8 + r); }
      float ndB = dist2e(bx[r], by[r], bz[r], wBx, wBy, wBz);
      float dvB = fminf(db[r], ndB);
      db[r] = dvB;
      if (dvB > bdB) { bdB = dvB; giB = (unsigned)(t * 8 + r); }
    }
    ull keyA = ((ull)__float_as_uint(bdA) << 32) | (ull)(unsigned)~giA;
    ull keyB = ((ull)__float_as_uint(bdB) << 32) | (ull)(unsigned)~giB;
    keyA = kred_all(keyA);
    keyB = kred_all(keyB);
    if (lane == 63) { kbA[par][wid] = keyA; kbB[par][wid] = keyB; }
    __syncthreads();
    ull mA = kbA[par][0], mB = kbB[par][0];
#pragma unroll
    for (int u = 1; u < 8; ++u) {
      ull a = kbA[par][u]; if (a > mA) mA = a;
      ull b2 = kbB[par][u]; if (b2 > mB) mB = b2;
    }
    const int wA = (int)~(unsigned)(mA & 0xffffffffULL);
    const int wB = (int)~(unsigned)(mB & 0xffffffffULL);
    wAx = xA[wA]; wAy = yA[wA]; wAz = zA[wA];   // overlapped uniform b32 reads
    wBx = xB[wB]; wBy = yB[wB]; wBz = zB[wB];
    if (t == 0) { whA[it] = wA; whB[it] = wB; }
  }
  __syncthreads();
  const size_t oAb = (size_t)bA * MC, oBb = (size_t)bB * MC;
  for (int s = t; s < MC; s += 512) {   // one-shot output writeback, both clouds
    int wa = whA[s], wb = whB[s];
    size_t o = oAb + s;
    float X = xA[wa], Y = yA[wa], Z = zA[wa];
    ctr[3*o] = X; ctr[3*o+1] = Y; ctr[3*o+2] = Z;
    cent_out[3*o] = X; cent_out[3*o+1] = Y; cent_out[3*o+2] = Z;
    batch_out[o] = (float)bA;
    o = oBb + s;
    X = xB[wb]; Y = yB[wb]; Z = zB[wb];
    ctr[3*o] = X; ctr[3*o+1] = Y; ctr[3*o+2] = Z;
    cent_out[3*o] = X; cent_out[3*o+1] = Y; cent_out[3*o+2] = Z;
    batch_out[o] = (float)bB;
  }
}

// ------------- Kernel 2: radius + K-nearest selection, one wave per center -------------
// Selection inner loop uses DPP u64 max-reduce (VALU pipe) on inverted keys
// ~(d2bits<<32|idx): u64 max == (min d2, tie -> lowest idx) — same semantics as
// the previous shfl comparator, ~2x cheaper per round (no DS-pipe hops).
__global__ void neigh_kernel(const float* __restrict__ point,
                             const float* __restrict__ ctr,
                             int* __restrict__ nidx, int* __restrict__ ncnt) {
  const int c = blockIdx.x;
  const int b = c >> 10;  // c / MC
  const int lane = threadIdx.x;  // 64 threads = 1 wave
  __shared__ float ld[512];
  __shared__ int li[512];
  const float R2 = (float)(0.2 * 0.2);
  const float cx = ctr[3*c], cy = ctr[3*c+1], cz = ctr[3*c+2];
  const float* p = point + (size_t)b * NP * 3;
  int cnt = 0;
  for (int s = 0; s < NP / 64; ++s) {   // compact in-ball candidates into LDS
    int j = s * 64 + lane;
    float d2 = dist2e(cx, cy, cz, p[3*j], p[3*j+1], p[3*j+2]);
    bool v = d2 < R2;
    unsigned long long m = __ballot(v);
    if (v) {
      int pos = cnt + __popcll(m & ((1ull << lane) - 1ull));
      if (pos < 512) { ld[pos] = d2; li[pos] = j; }
    }
    cnt += __popcll(m);
  }
  if (cnt > 512) cnt = 512;
  __syncthreads();
  if (cnt <= KNN) {
    nidx[(size_t)c * KNN + lane] = (lane < cnt) ? li[lane] : 0;
  } else {
    ull ok[8];
#pragma unroll
    for (int r = 0; r < 8; ++r) {
      int s2 = lane + r * 64;
      ok[r] = 0ull;
      if (s2 < cnt)
        ok[r] = ~(((ull)__float_as_uint(ld[s2]) << 32) | (ull)(unsigned)li[s2]);
    }
    for (int round = 0; round < KNN; ++round) {
      ull k = ok[0];
#pragma unroll
      for (int r = 1; r < 8; ++r) if (ok[r] > k) k = ok[r];
      k = kred_all(k);
      unsigned klo = (unsigned)__builtin_amdgcn_readlane((int)(unsigned)(k & 0xffffffffULL), 63);
      unsigned khi = (unsigned)__builtin_amdgcn_readlane((int)(unsigned)(k >> 32), 63);
      ull wkey = ((ull)khi << 32) | (ull)klo;
      if (lane == 0) nidx[(size_t)c * KNN + round] = (int)~klo;
#pragma unroll
      for (int r = 0; r < 8; ++r) if (ok[r] == wkey) ok[r] = 0ull;
    }
  }
  if (lane == 0) ncnt[c] = (cnt < KNN) ? cnt : KNN;
}

// ---------- Kernel 3: MFMA bf16 MLP, one wave per center, 4 centers/block ----------
#define HSTRIDE 72   // bf16 elems per hbuf row: 144 B = 16B-aligned, 2-way-conflict-free b128
__global__ __launch_bounds__(256) void mlp_kernel(
    const ushort_t* __restrict__ xyzbf, const float* __restrict__ point,
    const float* __restrict__ ctr, const int* __restrict__ nidx,
    const int* __restrict__ ncnt,
    const ushort_t* __restrict__ w1f, const ushort_t* __restrict__ w2f,
    const ushort_t* __restrict__ w3f,
    const float* __restrict__ b1, const float* __restrict__ b2,
    const float* __restrict__ b3,
    float* __restrict__ out) {
  const int wv = threadIdx.x >> 6, lane = threadIdx.x & 63;
  const int quad = lane >> 4, col16 = lane & 15;
  const int c = blockIdx.x * 4 + wv;
  const int bcl = c >> 10;
  const size_t bbase = (size_t)bcl * NP;
  __shared__ ushort_t hbuf_all[4 * 64 * HSTRIDE];  // 36864 B, wave-private slices
  ushort_t* hb = hbuf_all + wv * 64 * HSTRIDE;

  const int jg = nidx[(size_t)c * KNN + lane];
  const int nv = ncnt[c];
  const float cx = ctr[3*c], cy = ctr[3*c+1], cz = ctr[3*c+2];
  const float* pp = point + (bbase + jg) * 3;
  const float dx = pp[0] - cx, dy = pp[1] - cy, dz = pp[2] - cz;

  bf16x8 a1[4][2];
  bf16x8 a2[4];
#pragma unroll
  for (int mt = 0; mt < 4; ++mt) {
    int srcl = mt * 16 + col16;
    int jmt = __shfl(jg, srcl);
    const ushort_t* rp = xyzbf + (bbase + (size_t)jmt) * CIN + quad * 8;
    a1[mt][0] = *(const bf16x8*)(rp);
    a1[mt][1] = *(const bf16x8*)(rp + 32);
    float ddx = __shfl(dx, srcl), ddy = __shfl(dy, srcl), ddz = __shfl(dz, srcl);
    bf16x8 t2 = {0, 0, 0, 0, 0, 0, 0, 0};
    if (quad == 0) {
      t2[0] = (short)f2bf(ddx); t2[1] = (short)f2bf(ddy); t2[2] = (short)f2bf(ddz);
    }
    a2[mt] = t2;
  }

  bf16x8 bw1[4][3];
#pragma unroll
  for (int nt = 0; nt < 4; ++nt)
#pragma unroll
    for (int ks = 0; ks < 3; ++ks)
      bw1[nt][ks] = *(const bf16x8*)(w1f + ((size_t)(nt * 3 + ks) * 64 + lane) * 8);
  f32x4 acc1[4][4];
#pragma unroll
  for (int nt = 0; nt < 4; ++nt) {
    float bv = b1[nt * 16 + col16];
#pragma unroll
    for (int mt = 0; mt < 4; ++mt) { f32x4 v = {bv, bv, bv, bv}; acc1[mt][nt] = v; }
  }
#pragma unroll
  for (int mt = 0; mt < 4; ++mt)
#pragma unroll
    for (int nt = 0; nt < 4; ++nt) {
      acc1[mt][nt] = __builtin_amdgcn_mfma_f32_16x16x32_bf16(a1[mt][0], bw1[nt][0], acc1[mt][nt], 0, 0, 0);
      acc1[mt][nt] = __builtin_amdgcn_mfma_f32_16x16x32_bf16(a1[mt][1], bw1[nt][1], acc1[mt][nt], 0, 0, 0);
      acc1[mt][nt] = __builtin_amdgcn_mfma_f32_16x16x32_bf16(a2[mt],    bw1[nt][2], acc1[mt][nt], 0, 0, 0);
    }
#pragma unroll
  for (int mt = 0; mt < 4; ++mt)
#pragma unroll
    for (int nt = 0; nt < 4; ++nt)
#pragma unroll
      for (int reg = 0; reg < 4; ++reg) {
        int row = quad * 4 + reg + mt * 16;
        hb[row * HSTRIDE + col16 + nt * 16] = f2bf(fmaxf(acc1[mt][nt][reg], 0.f));
      }

  bf16x8 a21[4][2];
#pragma unroll
  for (int mt = 0; mt < 4; ++mt)
#pragma unroll
    for (int ks = 0; ks < 2; ++ks)
      a21[mt][ks] = *(const bf16x8*)(hb + (col16 + mt * 16) * HSTRIDE + ks * 32 + quad * 8);
  bf16x8 bw2[4][2];
#pragma unroll
  for (int nt = 0; nt < 4; ++nt)
#pragma unroll
    for (int ks = 0; ks < 2; ++ks)
      bw2[nt][ks] = *(const bf16x8*)(w2f + ((size_t)(nt * 2 + ks) * 64 + lane) * 8);
  f32x4 acc2[4][4];
#pragma unroll
  for (int nt = 0; nt < 4; ++nt) {
    float bv = b2[nt * 16 + col16];
#pragma unroll
    for (int mt = 0; mt < 4; ++mt) { f32x4 v = {bv, bv, bv, bv}; acc2[mt][nt] = v; }
  }
#pragma unroll
  for (int mt = 0; mt < 4; ++mt)
#pragma unroll
    for (int nt = 0; nt < 4; ++nt) {
      acc2[mt][nt] = __builtin_amdgcn_mfma_f32_16x16x32_bf16(a21[mt][0], bw2[nt][0], acc2[mt][nt], 0, 0, 0);
      acc2[mt][nt] = __builtin_amdgcn_mfma_f32_16x16x32_bf16(a21[mt][1], bw2[nt][1], acc2[mt][nt], 0, 0, 0);
    }
#pragma unroll
  for (int mt = 0; mt < 4; ++mt)
#pragma unroll
    for (int nt = 0; nt < 4; ++nt)
#pragma unroll
      for (int reg = 0; reg < 4; ++reg) {
        int row = quad * 4 + reg + mt * 16;
        hb[row * HSTRIDE + col16 + nt * 16] = f2bf(fmaxf(acc2[mt][nt][reg], 0.f));
      }

  bf16x8 a3[4][2];
#pragma unroll
  for (int mt = 0; mt < 4; ++mt)
#pragma unroll
    for (int ks = 0; ks < 2; ++ks)
      a3[mt][ks] = *(const bf16x8*)(hb + (col16 + mt * 16) * HSTRIDE + ks * 32 + quad * 8);
#pragma unroll
  for (int pass = 0; pass < 2; ++pass) {
    bf16x8 bw3[4][2];
#pragma unroll
    for (int nt = 0; nt < 4; ++nt)
#pragma unroll
      for (int ks = 0; ks < 2; ++ks)
        bw3[nt][ks] = *(const bf16x8*)(w3f + ((size_t)((pass * 4 + nt) * 2 + ks) * 64 + lane) * 8);
    f32x4 acc3[4][4];
#pragma unroll
    for (int nt = 0; nt < 4; ++nt) {
      float bv = b3[pass * 64 + nt * 16 + col16];
#pragma unroll
      for (int mt = 0; mt < 4; ++mt) { f32x4 v = {bv, bv, bv, bv}; acc3[mt][nt] = v; }
    }
#pragma unroll
    for (int mt = 0; mt < 4; ++mt)
#pragma unroll
      for (int nt = 0; nt < 4; ++nt) {
        acc3[mt][nt] = __builtin_amdgcn_mfma_f32_16x16x32_bf16(a3[mt][0], bw3[nt][0], acc3[mt][nt], 0, 0, 0);
        acc3[mt][nt] = __builtin_amdgcn_mfma_f32_16x16x32_bf16(a3[mt][1], bw3[nt][1], acc3[mt][nt], 0, 0, 0);
      }
#pragma unroll
    for (int nt = 0; nt < 4; ++nt) {
      float m = -1.0e30f;
#pragma unroll
      for (int mt = 0; mt < 4; ++mt)
#pragma unroll
        for (int reg = 0; reg < 4; ++reg) {
          int row = quad * 4 + reg + mt * 16;
          float v = fmaxf(acc3[mt][nt][reg], 0.f);
          m = fmaxf(m, (row < nv) ? v : -1.0e30f);
        }
      m = fmaxf(m, __shfl_xor(m, 16));
      m = fmaxf(m, __shfl_xor(m, 32));
      if (quad == 0)
        out[(size_t)c * OUTD + pass * 64 + nt * 16 + col16] = m;
    }
  }
}

extern "C" void kernel_launch(void* const* d_in, const int* in_sizes, int n_in,
                              void* d_out, int out_size, void* d_ws, size_t ws_size,
                              hipStream_t stream) {
  const float* xyz   = (const float*)d_in[0];
  const float* point = (const float*)d_in[1];
  // d_in[2] = batch (values == cloud index by construction), d_in[3] = num_samples (64)
  const float* W1 = (const float*)d_in[4];
  const float* b1 = (const float*)d_in[5];
  const float* W2 = (const float*)d_in[6];
  const float* b2 = (const float*)d_in[7];
  const float* W3 = (const float*)d_in[8];
  const float* b3 = (const float*)d_in[9];

  float* out       = (float*)d_out;                     // [16384,128]
  float* cent_out  = out + (size_t)NB * MC * OUTD;      // [16384,3]
  float* batch_out = cent_out + (size_t)NB * MC * 3;    // [16384] (f32 values)

  char* ws = (char*)d_ws;
  float* ctr       = (float*)(ws);                          // 196608 B
  int*   nidx      = (int*)(ws + 196608);                   // 4 MB
  int*   ncnt      = (int*)(ws + 196608 + 4194304);         // 64 KB
  ushort_t* xyzbf  = (ushort_t*)(ws + 4456448);             // 8 MB
  ushort_t* w1f    = (ushort_t*)(ws + 4456448 + 8388608);   // 12288 B
  ushort_t* w2f    = (ushort_t*)(ws + 12845056 + 12288);    // 8192 B
  ushort_t* w3f    = (ushort_t*)(ws + 12857344 + 8192);     // 16384 B

  // blocks 0..7: FPS (2 clouds each); blocks 8..2055: xyz->bf16; block 2056: weights
  fps_prep_kernel<<<NB / 2 + 2048 + 1, 512, 0, stream>>>(
      point, xyz, W1, W2, W3, ctr, cent_out, batch_out, xyzbf, w1f, w2f, w3f);
  neigh_kernel<<<NB * MC, 64, 0, stream>>>(point, ctr, nidx, ncnt);
  mlp_kernel<<<NB * MC / 4, 256, 0, stream>>>(xyzbf, point, ctr, nidx, ncnt,
                                              w1f, w2f, w3f, b1, b2, b3, out);
}

// Round 6
// 1249.187 us; speedup vs baseline: 1.4505x; 1.2769x over previous
//
#include <hip/hip_runtime.h>
#include <cstdint>

#define NB 16      // clouds
#define NP 4096    // points per cloud
#define MC 1024    // FPS centers per cloud
#define KNN 64     // neighbors
#define CIN 64     // input feature dim
#define HID 64
#define OUTD 128

typedef __attribute__((ext_vector_type(8))) short bf16x8;
typedef __attribute__((ext_vector_type(4))) float f32x4;
typedef unsigned long long ull;
typedef unsigned short ushort_t;

#define F32_INF __int_as_float(0x7f800000)

// Bit-exact (vs numpy f32) squared distance: no FMA contraction, numpy sum order.
__device__ __forceinline__ float dist2e(float ax, float ay, float az,
                                        float bx, float by, float bz) {
  float dx = __fsub_rn(ax, bx);
  float dy = __fsub_rn(ay, by);
  float dz = __fsub_rn(az, bz);
  return __fadd_rn(__fadd_rn(__fmul_rn(dx, dx), __fmul_rn(dy, dy)), __fmul_rn(dz, dz));
}

// f32 -> bf16 with round-to-nearest-even.
__device__ __forceinline__ ushort_t f2bf(float f) {
  unsigned u = __float_as_uint(f);
  unsigned r = (u + 0x7FFFu + ((u >> 16) & 1u)) >> 16;
  return (ushort_t)r;
}

// ---- DPP f32 max-reduce on the VALU pipe (validated ctrl sequence from r2/r3) ----
template <int CTRL>
__device__ __forceinline__ float fshift(float x) {
  int v = __builtin_amdgcn_update_dpp(__float_as_int(x), __float_as_int(x),
                                      CTRL, 0xf, 0xf, false);
  return __int_as_float(v);
}
__device__ __forceinline__ float fmax_wave(float m) {
  m = fmaxf(m, fshift<0x111>(m));  // row_shr:1
  m = fmaxf(m, fshift<0x112>(m));  // row_shr:2
  m = fmaxf(m, fshift<0x114>(m));  // row_shr:4
  m = fmaxf(m, fshift<0x118>(m));  // row_shr:8
  m = fmaxf(m, fshift<0x142>(m));  // row_bcast:15
  m = fmaxf(m, fshift<0x143>(m));  // row_bcast:31 -> lane 63 = wave max
  return m;
}

// ---------- Prep helper: W -> MFMA B-fragment layout ----------
__device__ __forceinline__ void wfrag_entry(const float* __restrict__ W,
                                            ushort_t* __restrict__ out,
                                            int e, int KS, int K, int N) {
  int lane = e & 63, t2 = e >> 6;
  int ks = t2 % KS, nt = t2 / KS;
  int n = nt * 16 + (lane & 15);
  int kb = ks * 32 + ((lane >> 4) & 3) * 8;
#pragma unroll
  for (int j = 0; j < 8; ++j) {
    int k = kb + j;
    float v = (k < K) ? W[(size_t)k * N + n] : 0.f;
    out[(size_t)e * 8 + j] = f2bf(v);
  }
}

// ============ Kernel 1 (fused): FPS (blocks 0..15, 1 cloud each) + prep (rest) ============
// FPS per iter: dist+inline-coord-track -> f32 DPP wave max -> ballot picks lowest
// winning lane (gi = t*16+r is lex-monotone => first-occurrence argmax, matches numpy)
// -> winner writes {bd, gi, x, y} + {z} to parity kbuf -> barrier -> uniform read +
// 3-stage (bd desc, gi asc) select. No index history: downstream needs only coords.
__global__ __launch_bounds__(256) void fps_prep_kernel(
    const float* __restrict__ point, const float* __restrict__ xyz,
    const float* __restrict__ W1, const float* __restrict__ W2, const float* __restrict__ W3,
    float* __restrict__ ctr, float* __restrict__ cent_out, float* __restrict__ batch_out,
    ushort_t* __restrict__ xyzbf, ushort_t* __restrict__ w1f,
    ushort_t* __restrict__ w2f, ushort_t* __restrict__ w3f) {
  const int blk = blockIdx.x;
  const int t = threadIdx.x;
  if (blk >= NB) {  // ---- prep path (independent of FPS; runs on idle CUs) ----
    const int pb = blk - NB;
    if (pb < 4096) {
      size_t i = ((size_t)pb * 256 + t) * 4;
      float4 v = *(const float4*)(xyz + i);
      unsigned lo = (unsigned)f2bf(v.x) | ((unsigned)f2bf(v.y) << 16);
      unsigned hi = (unsigned)f2bf(v.z) | ((unsigned)f2bf(v.w) << 16);
      uint2 o; o.x = lo; o.y = hi;
      *(uint2*)(xyzbf + i) = o;
    } else {
      for (int e = t; e < 4 * 3 * 64; e += 256) wfrag_entry(W1, w1f, e, 3, CIN + 3, HID);
      for (int e = t; e < 4 * 2 * 64; e += 256) wfrag_entry(W2, w2f, e, 2, HID, HID);
      for (int e = t; e < 8 * 2 * 64; e += 256) wfrag_entry(W3, w3f, e, 2, HID, OUTD);
    }
    return;
  }
  // ---- FPS path ----
  const int b = blk;
  const int lane = t & 63, wid = t >> 6;
  __shared__ float4 kbufA[2][4];   // {bd, giF, x, y} per wave, parity-buffered
  __shared__ float  kbufZ[2][4];   // {z}
  __shared__ float4 chist[MC];     // 16 KB center-coordinate history
  const float* p = point + (size_t)b * NP * 3;
  float qx[16], qy[16], qz[16], d[16];
#pragma unroll
  for (int r = 0; r < 16; ++r) {   // one-time global read; NO pts LDS needed
    int i = t * 16 + r;
    qx[r] = p[3 * i]; qy[r] = p[3 * i + 1]; qz[r] = p[3 * i + 2];
    d[r] = F32_INF;                // min(inf, d0) == d0 exactly
  }
  float wx = p[0], wy = p[1], wz = p[2];   // sample 0 is point 0
  if (t == 0) { float4 c0; c0.x = wx; c0.y = wy; c0.z = wz; c0.w = 0.f; chist[0] = c0; }
  for (int it = 1; it < MC; ++it) {
    const int par = it & 1;
    float bd = -1.0f; int br = 0;
    float cx = 0.f, cy = 0.f, cz = 0.f;
#pragma unroll
    for (int r = 0; r < 16; ++r) {  // fused min-update + first-max argmax + coord track
      float nd = dist2e(qx[r], qy[r], qz[r], wx, wy, wz);
      float dv = fminf(d[r], nd);
      d[r] = dv;
      if (dv > bd) { bd = dv; br = r; cx = qx[r]; cy = qy[r]; cz = qz[r]; }
    }
    const float wmax = __int_as_float(
        __builtin_amdgcn_readlane(__float_as_int(fmax_wave(bd)), 63));
    const ull msk = __ballot(bd == wmax);
    const int firstl = __ffsll(msk) - 1;   // lowest lane with max -> lowest gi
    if (lane == firstl) {
      float4 e; e.x = bd; e.y = (float)(t * 16 + br); e.z = cx; e.w = cy;
      kbufA[par][wid] = e;
      kbufZ[par][wid] = cz;
    }
    __syncthreads();
    const float4 e0 = kbufA[par][0], e1 = kbufA[par][1];
    const float4 e2 = kbufA[par][2], e3 = kbufA[par][3];
    const float z0 = kbufZ[par][0], z1 = kbufZ[par][1];
    const float z2 = kbufZ[par][2], z3 = kbufZ[par][3];
    const bool s01 = (e0.x > e1.x) || (e0.x == e1.x && e0.y < e1.y);
    float4 ea = s01 ? e0 : e1; float za = s01 ? z0 : z1;
    const bool s23 = (e2.x > e3.x) || (e2.x == e3.x && e2.y < e3.y);
    float4 eb = s23 ? e2 : e3; float zb = s23 ? z2 : z3;
    const bool sab = (ea.x > eb.x) || (ea.x == eb.x && ea.y < eb.y);
    wx = sab ? ea.z : eb.z;
    wy = sab ? ea.w : eb.w;
    wz = sab ? za : zb;
    if (t == 0) { float4 cc; cc.x = wx; cc.y = wy; cc.z = wz; cc.w = 0.f; chist[it] = cc; }
  }
  __syncthreads();
  for (int s = t; s < MC; s += 256) {      // one-shot output writeback from chist
    float4 cv = chist[s];
    size_t o = (size_t)b * MC + s;
    ctr[3*o] = cv.x; ctr[3*o+1] = cv.y; ctr[3*o+2] = cv.z;
    cent_out[3*o] = cv.x; cent_out[3*o+1] = cv.y; cent_out[3*o+2] = cv.z;
    batch_out[o] = (float)b;  // batch = arange // NP == cloud index
  }
}

// ------------- Kernel 2: radius + K-nearest selection, one wave per center -------------
// (round-3 proven version: shfl comparator, no outliers observed)
__global__ void neigh_kernel(const float* __restrict__ point,
                             const float* __restrict__ ctr,
                             int* __restrict__ nidx, int* __restrict__ ncnt) {
  const int c = blockIdx.x;
  const int b = c >> 10;  // c / MC
  const int lane = threadIdx.x;  // 64 threads = 1 wave
  __shared__ float ld[512];
  __shared__ int li[512];
  const float R2 = (float)(0.2 * 0.2);
  const float cx = ctr[3*c], cy = ctr[3*c+1], cz = ctr[3*c+2];
  const float* p = point + (size_t)b * NP * 3;
  int cnt = 0;
  for (int s = 0; s < NP / 64; ++s) {
    int j = s * 64 + lane;
    float d2 = dist2e(cx, cy, cz, p[3*j], p[3*j+1], p[3*j+2]);
    bool v = d2 < R2;
    unsigned long long m = __ballot(v);
    if (v) {
      int pos = cnt + __popcll(m & ((1ull << lane) - 1ull));
      if (pos < 512) { ld[pos] = d2; li[pos] = j; }
    }
    cnt += __popcll(m);
  }
  if (cnt > 512) cnt = 512;
  __syncthreads();
  if (cnt <= KNN) {
    nidx[(size_t)c * KNN + lane] = (lane < cnt) ? li[lane] : 0;
  } else {
    float od[8]; int oi[8];
#pragma unroll
    for (int r = 0; r < 8; ++r) {
      int s2 = lane + r * 64;
      if (s2 < cnt) { od[r] = ld[s2]; oi[r] = li[s2]; }
      else { od[r] = F32_INF; oi[r] = 0x7fffffff; }
    }
    for (int round = 0; round < KNN; ++round) {
      float bd = F32_INF; int bi = 0x7fffffff;
#pragma unroll
      for (int r = 0; r < 8; ++r)
        if (od[r] < bd || (od[r] == bd && oi[r] < bi)) { bd = od[r]; bi = oi[r]; }
#pragma unroll
      for (int off = 32; off > 0; off >>= 1) {
        float o2 = __shfl_down(bd, off);
        int i2 = __shfl_down(bi, off);
        if (o2 < bd || (o2 == bd && i2 < bi)) { bd = o2; bi = i2; }
      }
      bi = __shfl(bi, 0);
      if (lane == 0) nidx[(size_t)c * KNN + round] = bi;
#pragma unroll
      for (int r = 0; r < 8; ++r) if (oi[r] == bi) od[r] = F32_INF;
    }
  }
  if (lane == 0) ncnt[c] = (cnt < KNN) ? cnt : KNN;
}

// ---------- Kernel 3: MFMA bf16 MLP, one wave per center, 4 centers/block ----------
#define HSTRIDE 72   // bf16 elems per hbuf row: 144 B = 16B-aligned, 2-way-conflict-free b128
__global__ __launch_bounds__(256) void mlp_kernel(
    const ushort_t* __restrict__ xyzbf, const float* __restrict__ point,
    const float* __restrict__ ctr, const int* __restrict__ nidx,
    const int* __restrict__ ncnt,
    const ushort_t* __restrict__ w1f, const ushort_t* __restrict__ w2f,
    const ushort_t* __restrict__ w3f,
    const float* __restrict__ b1, const float* __restrict__ b2,
    const float* __restrict__ b3,
    float* __restrict__ out) {
  const int wv = threadIdx.x >> 6, lane = threadIdx.x & 63;
  const int quad = lane >> 4, col16 = lane & 15;
  const int c = blockIdx.x * 4 + wv;
  const int bcl = c >> 10;
  const size_t bbase = (size_t)bcl * NP;
  __shared__ ushort_t hbuf_all[4 * 64 * HSTRIDE];  // 36864 B, wave-private slices
  ushort_t* hb = hbuf_all + wv * 64 * HSTRIDE;

  const int jg = nidx[(size_t)c * KNN + lane];
  const int nv = ncnt[c];
  const float cx = ctr[3*c], cy = ctr[3*c+1], cz = ctr[3*c+2];
  const float* pp = point + (bbase + jg) * 3;
  const float dx = pp[0] - cx, dy = pp[1] - cy, dz = pp[2] - cz;

  bf16x8 a1[4][2];
  bf16x8 a2[4];
#pragma unroll
  for (int mt = 0; mt < 4; ++mt) {
    int srcl = mt * 16 + col16;
    int jmt = __shfl(jg, srcl);
    const ushort_t* rp = xyzbf + (bbase + (size_t)jmt) * CIN + quad * 8;
    a1[mt][0] = *(const bf16x8*)(rp);
    a1[mt][1] = *(const bf16x8*)(rp + 32);
    float ddx = __shfl(dx, srcl), ddy = __shfl(dy, srcl), ddz = __shfl(dz, srcl);
    bf16x8 t2 = {0, 0, 0, 0, 0, 0, 0, 0};
    if (quad == 0) {
      t2[0] = (short)f2bf(ddx); t2[1] = (short)f2bf(ddy); t2[2] = (short)f2bf(ddz);
    }
    a2[mt] = t2;
  }

  bf16x8 bw1[4][3];
#pragma unroll
  for (int nt = 0; nt < 4; ++nt)
#pragma unroll
    for (int ks = 0; ks < 3; ++ks)
      bw1[nt][ks] = *(const bf16x8*)(w1f + ((size_t)(nt * 3 + ks) * 64 + lane) * 8);
  f32x4 acc1[4][4];
#pragma unroll
  for (int nt = 0; nt < 4; ++nt) {
    float bv = b1[nt * 16 + col16];
#pragma unroll
    for (int mt = 0; mt < 4; ++mt) { f32x4 v = {bv, bv, bv, bv}; acc1[mt][nt] = v; }
  }
#pragma unroll
  for (int mt = 0; mt < 4; ++mt)
#pragma unroll
    for (int nt = 0; nt < 4; ++nt) {
      acc1[mt][nt] = __builtin_amdgcn_mfma_f32_16x16x32_bf16(a1[mt][0], bw1[nt][0], acc1[mt][nt], 0, 0, 0);
      acc1[mt][nt] = __builtin_amdgcn_mfma_f32_16x16x32_bf16(a1[mt][1], bw1[nt][1], acc1[mt][nt], 0, 0, 0);
      acc1[mt][nt] = __builtin_amdgcn_mfma_f32_16x16x32_bf16(a2[mt],    bw1[nt][2], acc1[mt][nt], 0, 0, 0);
    }
#pragma unroll
  for (int mt = 0; mt < 4; ++mt)
#pragma unroll
    for (int nt = 0; nt < 4; ++nt)
#pragma unroll
      for (int reg = 0; reg < 4; ++reg) {
        int row = quad * 4 + reg + mt * 16;
        hb[row * HSTRIDE + col16 + nt * 16] = f2bf(fmaxf(acc1[mt][nt][reg], 0.f));
      }

  bf16x8 a21[4][2];
#pragma unroll
  for (int mt = 0; mt < 4; ++mt)
#pragma unroll
    for (int ks = 0; ks < 2; ++ks)
      a21[mt][ks] = *(const bf16x8*)(hb + (col16 + mt * 16) * HSTRIDE + ks * 32 + quad * 8);
  bf16x8 bw2[4][2];
#pragma unroll
  for (int nt = 0; nt < 4; ++nt)
#pragma unroll
    for (int ks = 0; ks < 2; ++ks)
      bw2[nt][ks] = *(const bf16x8*)(w2f + ((size_t)(nt * 2 + ks) * 64 + lane) * 8);
  f32x4 acc2[4][4];
#pragma unroll
  for (int nt = 0; nt < 4; ++nt) {
    float bv = b2[nt * 16 + col16];
#pragma unroll
    for (int mt = 0; mt < 4; ++mt) { f32x4 v = {bv, bv, bv, bv}; acc2[mt][nt] = v; }
  }
#pragma unroll
  for (int mt = 0; mt < 4; ++mt)
#pragma unroll
    for (int nt = 0; nt < 4; ++nt) {
      acc2[mt][nt] = __builtin_amdgcn_mfma_f32_16x16x32_bf16(a21[mt][0], bw2[nt][0], acc2[mt][nt], 0, 0, 0);
      acc2[mt][nt] = __builtin_amdgcn_mfma_f32_16x16x32_bf16(a21[mt][1], bw2[nt][1], acc2[mt][nt], 0, 0, 0);
    }
#pragma unroll
  for (int mt = 0; mt < 4; ++mt)
#pragma unroll
    for (int nt = 0; nt < 4; ++nt)
#pragma unroll
      for (int reg = 0; reg < 4; ++reg) {
        int row = quad * 4 + reg + mt * 16;
        hb[row * HSTRIDE + col16 + nt * 16] = f2bf(fmaxf(acc2[mt][nt][reg], 0.f));
      }

  bf16x8 a3[4][2];
#pragma unroll
  for (int mt = 0; mt < 4; ++mt)
#pragma unroll
    for (int ks = 0; ks < 2; ++ks)
      a3[mt][ks] = *(const bf16x8*)(hb + (col16 + mt * 16) * HSTRIDE + ks * 32 + quad * 8);
#pragma unroll
  for (int pass = 0; pass < 2; ++pass) {
    bf16x8 bw3[4][2];
#pragma unroll
    for (int nt = 0; nt < 4; ++nt)
#pragma unroll
      for (int ks = 0; ks < 2; ++ks)
        bw3[nt][ks] = *(const bf16x8*)(w3f + ((size_t)((pass * 4 + nt) * 2 + ks) * 64 + lane) * 8);
    f32x4 acc3[4][4];
#pragma unroll
    for (int nt = 0; nt < 4; ++nt) {
      float bv = b3[pass * 64 + nt * 16 + col16];
#pragma unroll
      for (int mt = 0; mt < 4; ++mt) { f32x4 v = {bv, bv, bv, bv}; acc3[mt][nt] = v; }
    }
#pragma unroll
    for (int mt = 0; mt < 4; ++mt)
#pragma unroll
      for (int nt = 0; nt < 4; ++nt) {
        acc3[mt][nt] = __builtin_amdgcn_mfma_f32_16x16x32_bf16(a3[mt][0], bw3[nt][0], acc3[mt][nt], 0, 0, 0);
        acc3[mt][nt] = __builtin_amdgcn_mfma_f32_16x16x32_bf16(a3[mt][1], bw3[nt][1], acc3[mt][nt], 0, 0, 0);
      }
#pragma unroll
    for (int nt = 0; nt < 4; ++nt) {
      float m = -1.0e30f;
#pragma unroll
      for (int mt = 0; mt < 4; ++mt)
#pragma unroll
        for (int reg = 0; reg < 4; ++reg) {
          int row = quad * 4 + reg + mt * 16;
          float v = fmaxf(acc3[mt][nt][reg], 0.f);
          m = fmaxf(m, (row < nv) ? v : -1.0e30f);
        }
      m = fmaxf(m, __shfl_xor(m, 16));
      m = fmaxf(m, __shfl_xor(m, 32));
      if (quad == 0)
        out[(size_t)c * OUTD + pass * 64 + nt * 16 + col16] = m;
    }
  }
}

extern "C" void kernel_launch(void* const* d_in, const int* in_sizes, int n_in,
                              void* d_out, int out_size, void* d_ws, size_t ws_size,
                              hipStream_t stream) {
  const float* xyz   = (const float*)d_in[0];
  const float* point = (const float*)d_in[1];
  // d_in[2] = batch (values == cloud index by construction), d_in[3] = num_samples (64)
  const float* W1 = (const float*)d_in[4];
  const float* b1 = (const float*)d_in[5];
  const float* W2 = (const float*)d_in[6];
  const float* b2 = (const float*)d_in[7];
  const float* W3 = (const float*)d_in[8];
  const float* b3 = (const float*)d_in[9];

  float* out       = (float*)d_out;                     // [16384,128]
  float* cent_out  = out + (size_t)NB * MC * OUTD;      // [16384,3]
  float* batch_out = cent_out + (size_t)NB * MC * 3;    // [16384] (f32 values)

  char* ws = (char*)d_ws;
  float* ctr       = (float*)(ws);                          // 196608 B
  int*   nidx      = (int*)(ws + 196608);                   // 4 MB
  int*   ncnt      = (int*)(ws + 196608 + 4194304);         // 64 KB
  ushort_t* xyzbf  = (ushort_t*)(ws + 4456448);             // 8 MB
  ushort_t* w1f    = (ushort_t*)(ws + 4456448 + 8388608);   // 12288 B
  ushort_t* w2f    = (ushort_t*)(ws + 12845056 + 12288);    // 8192 B
  ushort_t* w3f    = (ushort_t*)(ws + 12857344 + 8192);     // 16384 B

  // blocks 0..15: FPS (1 cloud each); blocks 16..4111: xyz->bf16; block 4112: weights
  fps_prep_kernel<<<NB + 4096 + 1, 256, 0, stream>>>(
      point, xyz, W1, W2, W3, ctr, cent_out, batch_out, xyzbf, w1f, w2f, w3f);
  neigh_kernel<<<NB * MC, 64, 0, stream>>>(point, ctr, nidx, ncnt);
  mlp_kernel<<<NB * MC / 4, 256, 0, stream>>>(xyzbf, point, ctr, nidx, ncnt,
                                              w1f, w2f, w3f, b1, b2, b3, out);
}